// Round 2
// baseline (326.972 us; speedup 1.0000x reference)
//
#include <hip/hip_runtime.h>
#include <cmath>

// out[b] = X_b (Wq Wk^T) (X_b^T X_b) / 768^1.5   (47 GF factorized)
// R2: ONE persistent mega-kernel, 256 blocks x 256 threads (1 block/CU).
//   8 batch-teams of 32 blocks (team = blockIdx.x & 7 -> XCD-pinned under
//   round-robin dispatch; correctness does NOT depend on the mapping).
//   phase 0: per-team transpose X_b -> Xt_b (bf16 [D][S]) + Xbf_b (bf16 [S][D]);
//            64 blocks also compute P = Wq*Wk^T (96x96 tiles) straight from fp32.
//            -> ONE global barrier (makes Xt/Xbf/P device-visible).
//   per team (team-local barriers only; teams skew freely):
//     G_b  = Xt_b*Xt_b^T   64 tiles 96x96 K=2048 -> 2 tiles/block exact
//     Ht_b = a*G_b*P^T     64 tiles 96x96 K=768  -> 2 tiles/block exact
//     out_b= Xbf_b*Ht_b^T  96 tiles 128x128 K=768-> 3 tiles/block exact
//   All sync via sense-reversing atomic barriers in __device__ globals
//   (zero-init at module load, self-resetting across graph replays; immune
//   to the harness's ws poison-fill). __threadfence() release/acquire around
//   arrivals handles cross-XCD L2 non-coherence (whole-L2 wbl2/inv).
// MFMA bf16 16x16x32, BK=64, fp32 accum, glds width-16 staging, XOR chunk
// swizzle (bank-conflict-free), 2-phase LDS double-buffer in the K-loop.

typedef __attribute__((ext_vector_type(8))) short short8;
typedef __attribute__((ext_vector_type(4))) float f32x4;

__device__ __forceinline__ unsigned short f2bf(float f) {
    union { float f; unsigned int u; } v; v.f = f;
    unsigned int u = v.u;
    return (unsigned short)((u + 0x7FFFu + ((u >> 16) & 1u)) >> 16);  // RNE
}

// ---- persistent barrier state (NOT in ws: ws is poison-filled each iter) ----
__device__ unsigned g_gbar[64];      // [0]=cnt, [16]=gen   (global, n=256)
__device__ unsigned g_tbar[8][64];   // per-team [0]=cnt, [16]=gen (n=32)

__device__ __forceinline__ void abarrier(unsigned* cnt, unsigned* gen, unsigned n)
{
    __syncthreads();                       // drain this block's stores to L2
    if (threadIdx.x == 0) {
        __threadfence();                   // release: wbl2 this XCD's L2
        unsigned g = __hip_atomic_load(gen, __ATOMIC_RELAXED, __HIP_MEMORY_SCOPE_AGENT);
        unsigned c = __hip_atomic_fetch_add(cnt, 1u, __ATOMIC_ACQ_REL, __HIP_MEMORY_SCOPE_AGENT);
        if (c == n - 1u) {
            __hip_atomic_store(cnt, 0u, __ATOMIC_RELAXED, __HIP_MEMORY_SCOPE_AGENT);
            __hip_atomic_store(gen, g + 1u, __ATOMIC_RELEASE, __HIP_MEMORY_SCOPE_AGENT);
        } else {
            while (__hip_atomic_load(gen, __ATOMIC_RELAXED, __HIP_MEMORY_SCOPE_AGENT) == g)
                __builtin_amdgcn_s_sleep(2);
        }
        __threadfence();                   // acquire: invalidate stale lines
    }
    __syncthreads();
}

// ---- glds staging: ROWS x 64 bf16 tile -> LDS, 16B chunks, XOR swizzle ----
template <int ROWS>
__device__ __forceinline__ void stage_glds(const unsigned short* src, unsigned short* lds,
                                           int ld, int tid)
{
    #pragma unroll
    for (int it = 0; it < ROWS / 32; ++it) {
        int slot = it * 256 + tid;
        int r = slot >> 3, c = slot & 7;
        const unsigned short* gp = src + (size_t)r * ld + ((c ^ (r & 7)) << 3);
        unsigned short* lp = lds + (size_t)(it * 256 + (tid & 192)) * 8;  // wave-uniform base
        __builtin_amdgcn_global_load_lds(
            (__attribute__((address_space(1))) void*)(void*)gp,
            (__attribute__((address_space(3))) void*)lp, 16, 0, 0);
    }
}

// ---- fp32 reg staging (for P from fp32 W): convert + swizzled ds_write ----
template <int ROWS>
__device__ __forceinline__ void stage_f32(const float* __restrict__ src, unsigned short* lds,
                                          int ld, int tid)
{
    #pragma unroll
    for (int it = 0; it < ROWS / 32; ++it) {
        int slot = it * 256 + tid;
        int r = slot >> 3, c = slot & 7;
        const float* gp = src + (size_t)r * ld + c * 8;
        float4 a = *reinterpret_cast<const float4*>(gp);
        float4 d = *reinterpret_cast<const float4*>(gp + 4);
        union { short8 s; unsigned short u[8]; } v;
        v.u[0] = f2bf(a.x); v.u[1] = f2bf(a.y); v.u[2] = f2bf(a.z); v.u[3] = f2bf(a.w);
        v.u[4] = f2bf(d.x); v.u[5] = f2bf(d.y); v.u[6] = f2bf(d.z); v.u[7] = f2bf(d.w);
        *reinterpret_cast<short8*>(&lds[r * 64 + ((c ^ (r & 7)) << 3)]) = v.s;
    }
}

__device__ __forceinline__ void store_c(float* C, size_t i, float v) { C[i] = v; }
__device__ __forceinline__ void store_c(unsigned short* C, size_t i, float v) { C[i] = f2bf(v); }

// ---- one output tile: C[TMxTN] = alpha * A[TM,K] * B[TN,K]^T, dbuf K-loop ----
template <int TM, int TN, typename CT>
__device__ void gemm_tile(const unsigned short* __restrict__ A0,
                          const unsigned short* __restrict__ B0,
                          CT* __restrict__ C, int rowBase, int colBase,
                          int K, int lda, int ldb, int ldc, float alpha,
                          unsigned short* lds)
{
    constexpr int FM = TM / 32, FN = TN / 32;
    const int tid = threadIdx.x, lane = tid & 63, wave = tid >> 6;
    const int wr = (wave >> 1) * (TM / 2), wc = (wave & 1) * (TN / 2);
    const int l15 = lane & 15, quad = lane >> 4;
    unsigned short* Al[2] = { lds,           lds + (TM + TN) * 64 };
    unsigned short* Bl[2] = { lds + TM * 64, lds + (TM + TN) * 64 + TM * 64 };

    f32x4 acc[FM][FN] = {};
    stage_glds<TM>(A0, Al[0], lda, tid);
    stage_glds<TN>(B0, Bl[0], ldb, tid);
    __syncthreads();

    const int nt = K >> 6;
    for (int t = 0; t < nt; ++t) {
        const int cur = t & 1;
        if (t + 1 < nt) {
            stage_glds<TM>(A0 + (t + 1) * 64, Al[cur ^ 1], lda, tid);
            stage_glds<TN>(B0 + (t + 1) * 64, Bl[cur ^ 1], ldb, tid);
        }
        short8 af[FM][2], bfr[FN][2];
        #pragma unroll
        for (int i = 0; i < FM; ++i) {
            int ra = wr + i * 16 + l15;
            af[i][0] = *reinterpret_cast<const short8*>(&Al[cur][ra * 64 + ((quad ^ (ra & 7)) << 3)]);
            af[i][1] = *reinterpret_cast<const short8*>(&Al[cur][ra * 64 + (((quad + 4) ^ (ra & 7)) << 3)]);
        }
        #pragma unroll
        for (int i = 0; i < FN; ++i) {
            int rb = wc + i * 16 + l15;
            bfr[i][0] = *reinterpret_cast<const short8*>(&Bl[cur][rb * 64 + ((quad ^ (rb & 7)) << 3)]);
            bfr[i][1] = *reinterpret_cast<const short8*>(&Bl[cur][rb * 64 + (((quad + 4) ^ (rb & 7)) << 3)]);
        }
        #pragma unroll
        for (int ks = 0; ks < 2; ++ks)
            #pragma unroll
            for (int mi = 0; mi < FM; ++mi)
                #pragma unroll
                for (int ni = 0; ni < FN; ++ni)
                    acc[mi][ni] = __builtin_amdgcn_mfma_f32_16x16x32_bf16(
                        af[mi][ks], bfr[ni][ks], acc[mi][ni], 0, 0, 0);
        __syncthreads();
    }

    // C/D layout (m89-verified): col = lane&15, row = quad*4 + reg
    #pragma unroll
    for (int mi = 0; mi < FM; ++mi)
        #pragma unroll
        for (int ni = 0; ni < FN; ++ni) {
            int col = colBase + wc + ni * 16 + l15;
            #pragma unroll
            for (int r = 0; r < 4; ++r) {
                int row = rowBase + wr + mi * 16 + quad * 4 + r;
                store_c(C, (size_t)row * ldc + col, alpha * acc[mi][ni][r]);
            }
        }
}

// ---- P tile (96x96) from fp32 Wq,Wk: P = Wq * Wk^T, K=768, single-buffer ----
__device__ void ptile(const float* __restrict__ Wq, const float* __restrict__ Wk,
                      unsigned short* __restrict__ P, int ty, int tz,
                      unsigned short* lds)
{
    unsigned short* Al = lds;
    unsigned short* Bl = lds + 96 * 64;
    const int tid = threadIdx.x, lane = tid & 63, wave = tid >> 6;
    const int wr = (wave >> 1) * 48, wc = (wave & 1) * 48;
    const int l15 = lane & 15, quad = lane >> 4;
    f32x4 acc[3][3] = {};

    for (int k0 = 0; k0 < 768; k0 += 64) {
        stage_f32<96>(Wq + (size_t)(ty * 96) * 768 + k0, Al, 768, tid);
        stage_f32<96>(Wk + (size_t)(tz * 96) * 768 + k0, Bl, 768, tid);
        __syncthreads();
        short8 af[3][2], bfr[3][2];
        #pragma unroll
        for (int i = 0; i < 3; ++i) {
            int ra = wr + i * 16 + l15;
            af[i][0] = *reinterpret_cast<const short8*>(&Al[ra * 64 + ((quad ^ (ra & 7)) << 3)]);
            af[i][1] = *reinterpret_cast<const short8*>(&Al[ra * 64 + (((quad + 4) ^ (ra & 7)) << 3)]);
        }
        #pragma unroll
        for (int i = 0; i < 3; ++i) {
            int rb = wc + i * 16 + l15;
            bfr[i][0] = *reinterpret_cast<const short8*>(&Bl[rb * 64 + ((quad ^ (rb & 7)) << 3)]);
            bfr[i][1] = *reinterpret_cast<const short8*>(&Bl[rb * 64 + (((quad + 4) ^ (rb & 7)) << 3)]);
        }
        #pragma unroll
        for (int ks = 0; ks < 2; ++ks)
            #pragma unroll
            for (int mi = 0; mi < 3; ++mi)
                #pragma unroll
                for (int ni = 0; ni < 3; ++ni)
                    acc[mi][ni] = __builtin_amdgcn_mfma_f32_16x16x32_bf16(
                        af[mi][ks], bfr[ni][ks], acc[mi][ni], 0, 0, 0);
        __syncthreads();
    }
    #pragma unroll
    for (int mi = 0; mi < 3; ++mi)
        #pragma unroll
        for (int ni = 0; ni < 3; ++ni) {
            int col = tz * 96 + wc + ni * 16 + l15;
            #pragma unroll
            for (int r = 0; r < 4; ++r) {
                int row = ty * 96 + wr + mi * 16 + quad * 4 + r;
                P[(size_t)row * 768 + col] = f2bf(acc[mi][ni][r]);
            }
        }
}

// ---- 32x32 transpose tile: X fp32 -> Xt bf16 [D][S] and Xbf bf16 [S][D] ----
__device__ void transp_tile(const float* __restrict__ X, unsigned short* __restrict__ Xt,
                            unsigned short* __restrict__ Xbf, int bb, int s0, int d0,
                            unsigned short* tbuf /* 32*36 */)
{
    const float* Xb = X + (size_t)bb * 2048 * 768;
    unsigned short* Xtb = Xt + (size_t)bb * 2048 * 768;
    unsigned short* Xbb = Xbf + (size_t)bb * 2048 * 768;
    const int tx = threadIdx.x & 7, ty = threadIdx.x >> 3;

    float4 v = *reinterpret_cast<const float4*>(&Xb[(size_t)(s0 + ty) * 768 + d0 + tx * 4]);
    ushort4 pk;
    pk.x = f2bf(v.x); pk.y = f2bf(v.y); pk.z = f2bf(v.z); pk.w = f2bf(v.w);
    *reinterpret_cast<ushort4*>(&Xbb[(size_t)(s0 + ty) * 768 + d0 + tx * 4]) = pk;
    tbuf[(tx * 4 + 0) * 36 + ty] = pk.x;
    tbuf[(tx * 4 + 1) * 36 + ty] = pk.y;
    tbuf[(tx * 4 + 2) * 36 + ty] = pk.z;
    tbuf[(tx * 4 + 3) * 36 + ty] = pk.w;
    __syncthreads();
    ushort4 o;
    o.x = tbuf[ty * 36 + tx * 4 + 0];
    o.y = tbuf[ty * 36 + tx * 4 + 1];
    o.z = tbuf[ty * 36 + tx * 4 + 2];
    o.w = tbuf[ty * 36 + tx * 4 + 3];
    *reinterpret_cast<ushort4*>(&Xtb[(size_t)(d0 + ty) * 2048 + s0 + tx * 4]) = o;
    __syncthreads();   // tbuf reused by next tile
}

// ---- the mega-kernel ----
__global__ __launch_bounds__(256, 1)
void mega(const float* __restrict__ X, const float* __restrict__ Wq,
          const float* __restrict__ Wk, float* __restrict__ out,
          unsigned short* __restrict__ Xt, unsigned short* __restrict__ Xbf,
          unsigned short* __restrict__ P16, unsigned short* __restrict__ G16,
          unsigned short* __restrict__ Ht16, float alpha)
{
    __shared__ unsigned short lds[32768];   // 64 KB: fits 128x128 dbuf / 96x96 dbuf / ptile / transpose
    const int r  = blockIdx.x;              // 0..255
    const int b  = r & 7;                   // batch / team (= XCD under round-robin)
    const int lr = r >> 3;                  // rank within team, 0..31
    const int tid = threadIdx.x;

    // ---- phase 0: P tiles (first 8 blocks of each team) + per-team transpose
    if (lr < 8) ptile(Wq, Wk, P16, lr, b, lds);    // tile (lr, b): 64 unique tiles
    {
        // team b transposes batch b: 1536 tiles; P-carrying blocks take fewer
        int cnt   = (lr < 8) ? 42 : 50;
        int start = (lr < 8) ? lr * 42 : 336 + (lr - 8) * 50;
        for (int i = 0; i < cnt; ++i) {
            int t = start + i;
            transp_tile(X, Xt, Xbf, b, (t & 63) * 32, (t >> 6) * 32, lds);
        }
    }
    abarrier(&g_gbar[0], &g_gbar[16], 256);        // Xt, Xbf, P device-visible

    // ---- phase G: G_b = Xt_b * Xt_b^T  (8x8 tiles of 96, K=2048) ----
    const unsigned short* Xtb = Xt + (size_t)b * 768 * 2048;
    unsigned short* Gb = G16 + (size_t)b * 768 * 768;
    for (int u = lr; u < 64; u += 32) {
        int ty = u >> 3, tz = u & 7;
        gemm_tile<96, 96, unsigned short>(
            Xtb + (size_t)ty * 96 * 2048, Xtb + (size_t)tz * 96 * 2048,
            Gb, ty * 96, tz * 96, 2048, 2048, 2048, 768, 1.0f, lds);
    }
    abarrier(&g_tbar[b][0], &g_tbar[b][16], 32);   // G_b visible to team

    // ---- phase Ht: Ht_b = alpha * G_b * P^T  (8x8 tiles of 96, K=768) ----
    unsigned short* Htb = Ht16 + (size_t)b * 768 * 768;
    for (int u = lr; u < 64; u += 32) {
        int ty = u >> 3, tz = u & 7;
        gemm_tile<96, 96, unsigned short>(
            Gb + (size_t)ty * 96 * 768, P16 + (size_t)tz * 96 * 768,
            Htb, ty * 96, tz * 96, 768, 768, 768, 768, alpha, lds);
    }
    abarrier(&g_tbar[b][0], &g_tbar[b][16], 32);   // Ht_b visible to team

    // ---- phase out: out_b = Xbf_b * Ht_b^T  (16x6 tiles of 128, K=768) ----
    const unsigned short* Xbb = Xbf + (size_t)b * 2048 * 768;
    float* outb = out + (size_t)b * 2048 * 768;
    for (int u = lr; u < 96; u += 32) {
        int ty = u / 6, tz = u % 6;
        gemm_tile<128, 128, float>(
            Xbb + (size_t)ty * 128 * 768, Htb + (size_t)tz * 128 * 768,
            outb, ty * 128, tz * 128, 768, 768, 768, 768, 1.0f, lds);
    }
}

extern "C" void kernel_launch(void* const* d_in, const int* in_sizes, int n_in,
                              void* d_out, int out_size, void* d_ws, size_t ws_size,
                              hipStream_t stream)
{
    const float* X  = (const float*)d_in[0];  // [8,2048,768] fp32
    const float* Wq = (const float*)d_in[2];  // [768,768]
    const float* Wk = (const float*)d_in[3];  // [768,768]
    float* out = (float*)d_out;               // [8,2048,768] fp32

    const int Bn = 8, S = 2048, D = 768;
    const float alpha = 1.0f / (768.0f * sqrtf(768.0f));  // 1/768^1.5
    const size_t szX  = (size_t)Bn * S * D;   // ushort elements
    const size_t szDD = (size_t)Bn * D * D;

    // ws: Xt16 | Xbf | P16 | G16 | Ht16   (~70.4 MB; barrier state lives in
    // __device__ globals, NOT in ws, because ws is poison-filled each iter)
    unsigned short* Xt16 = (unsigned short*)d_ws;
    unsigned short* Xbf  = Xt16 + szX;
    unsigned short* P16  = Xbf + szX;
    unsigned short* G16  = P16 + (size_t)D * D;
    unsigned short* Ht16 = G16 + szDD;

    mega<<<dim3(256), dim3(256), 0, stream>>>(X, Wq, Wk, out,
                                              Xt16, Xbf, P16, G16, Ht16, alpha);
}

// Round 3
// 199.806 us; speedup vs baseline: 1.6364x; 1.6364x over previous
//
#include <hip/hip_runtime.h>
#include <cmath>

// out[b] = X_b (Wq Wk^T) (X_b^T X_b) / 768^1.5   (47 GF factorized)
// R3: 4 stream-ordered kernels, m97-style single-buffer 2-barrier gemm bodies,
// co-residency-first (R2 lesson: blocks/CU is the latency-hiding mechanism):
//   prep : 144 P-tiles (64x64, fp32 W reg-staged->bf16) + 12288 transpose tiles
//          X fp32 -> Xt bf16 [D][S] + Xbf bf16 [S][D]       (one launch)
//   G    : split-K=2. G_ks_b = Xt_b[:,ks*1024:+1024] * (same)^T -> fp32 partials
//          Ga,Gb. 96x96 tiles, grid (8,8,16)=1024 = 4/CU (LDS 24KB, cap 6).
//   Ht   : Ht_b = alpha*(Ga_b+Gb_b)*P^T. A-staging reads BOTH fp32 partials,
//          adds, converts bf16 in regs (fp32-accum numerics preserved, no
//          reduce pass). 64x64 tiles, grid (8,12,12)=1152 = 4.5/CU.
//   out  : out_b = Xbf_b * Ht_b^T. 128x64 tiles, grid (8,16,12)=1536 = 6/CU
//          (LDS 24KB, cap 6 -> all resident; was 2-3/CU in R0/R1).
// MFMA bf16 16x16x32, BK=64, fp32 accum, glds width-16 staging, XOR chunk
// swizzle (SQ_LDS_BANK_CONFLICT=0 verified in earlier rounds).
// blockIdx.x = batch -> XCD pinning (b = linear%8 under round-robin).

typedef __attribute__((ext_vector_type(8))) short short8;
typedef __attribute__((ext_vector_type(4))) float f32x4;

__device__ __forceinline__ unsigned short f2bf(float f) {
    union { float f; unsigned int u; } v; v.f = f;
    unsigned int u = v.u;
    return (unsigned short)((u + 0x7FFFu + ((u >> 16) & 1u)) >> 16);  // RNE
}

// ---- glds staging: ROWS x 64 bf16 tile -> LDS, 16B chunks, XOR swizzle ----
template <int ROWS>
__device__ __forceinline__ void stage_glds(const unsigned short* src, unsigned short* lds,
                                           int ld, int tid)
{
    #pragma unroll
    for (int it = 0; it < ROWS / 32; ++it) {
        int slot = it * 256 + tid;
        int r = slot >> 3, c = slot & 7;
        const unsigned short* gp = src + (size_t)r * ld + ((c ^ (r & 7)) << 3);
        unsigned short* lp = lds + (size_t)(it * 256 + (tid & 192)) * 8;  // wave-uniform base
        __builtin_amdgcn_global_load_lds(
            (__attribute__((address_space(1))) void*)(void*)gp,
            (__attribute__((address_space(3))) void*)lp, 16, 0, 0);
    }
}

// ---- fp32 -> bf16 reg staging (P from fp32 W) ----
template <int ROWS>
__device__ __forceinline__ void stage_f32(const float* __restrict__ src, unsigned short* lds,
                                          int ld, int tid)
{
    #pragma unroll
    for (int it = 0; it < ROWS / 32; ++it) {
        int slot = it * 256 + tid;
        int r = slot >> 3, c = slot & 7;
        const float* gp = src + (size_t)r * ld + c * 8;
        float4 a = *reinterpret_cast<const float4*>(gp);
        float4 d = *reinterpret_cast<const float4*>(gp + 4);
        union { short8 s; unsigned short u[8]; } v;
        v.u[0] = f2bf(a.x); v.u[1] = f2bf(a.y); v.u[2] = f2bf(a.z); v.u[3] = f2bf(a.w);
        v.u[4] = f2bf(d.x); v.u[5] = f2bf(d.y); v.u[6] = f2bf(d.z); v.u[7] = f2bf(d.w);
        *reinterpret_cast<short8*>(&lds[r * 64 + ((c ^ (r & 7)) << 3)]) = v.s;
    }
}

// ---- fp32 PAIR staging: (a+b) -> bf16 (G split-K merge, fused into Ht) ----
template <int ROWS>
__device__ __forceinline__ void stage_f32pair(const float* __restrict__ a,
                                              const float* __restrict__ b,
                                              unsigned short* lds, int ld, int tid)
{
    #pragma unroll
    for (int it = 0; it < ROWS / 32; ++it) {
        int slot = it * 256 + tid;
        int r = slot >> 3, c = slot & 7;
        size_t off = (size_t)r * ld + c * 8;
        float4 a0 = *reinterpret_cast<const float4*>(a + off);
        float4 a1 = *reinterpret_cast<const float4*>(a + off + 4);
        float4 b0 = *reinterpret_cast<const float4*>(b + off);
        float4 b1 = *reinterpret_cast<const float4*>(b + off + 4);
        union { short8 s; unsigned short u[8]; } v;
        v.u[0] = f2bf(a0.x + b0.x); v.u[1] = f2bf(a0.y + b0.y);
        v.u[2] = f2bf(a0.z + b0.z); v.u[3] = f2bf(a0.w + b0.w);
        v.u[4] = f2bf(a1.x + b1.x); v.u[5] = f2bf(a1.y + b1.y);
        v.u[6] = f2bf(a1.z + b1.z); v.u[7] = f2bf(a1.w + b1.w);
        *reinterpret_cast<short8*>(&lds[r * 64 + ((c ^ (r & 7)) << 3)]) = v.s;
    }
}

// ---- one K-step of MFMAs from swizzled LDS tiles ----
template <int TM, int TN>
__device__ __forceinline__ void mfma_step(const unsigned short* __restrict__ Al,
                                          const unsigned short* __restrict__ Bl,
                                          f32x4 (&acc)[TM / 32][TN / 32],
                                          int wr, int wc, int l15, int quad)
{
    constexpr int FM = TM / 32, FN = TN / 32;
    short8 af[FM][2], bfr[FN][2];
    #pragma unroll
    for (int i = 0; i < FM; ++i) {
        int ra = wr + i * 16 + l15;
        af[i][0] = *reinterpret_cast<const short8*>(&Al[ra * 64 + ((quad ^ (ra & 7)) << 3)]);
        af[i][1] = *reinterpret_cast<const short8*>(&Al[ra * 64 + (((quad + 4) ^ (ra & 7)) << 3)]);
    }
    #pragma unroll
    for (int i = 0; i < FN; ++i) {
        int rb = wc + i * 16 + l15;
        bfr[i][0] = *reinterpret_cast<const short8*>(&Bl[rb * 64 + ((quad ^ (rb & 7)) << 3)]);
        bfr[i][1] = *reinterpret_cast<const short8*>(&Bl[rb * 64 + (((quad + 4) ^ (rb & 7)) << 3)]);
    }
    #pragma unroll
    for (int ks = 0; ks < 2; ++ks)
        #pragma unroll
        for (int mi = 0; mi < FM; ++mi)
            #pragma unroll
            for (int ni = 0; ni < FN; ++ni)
                acc[mi][ni] = __builtin_amdgcn_mfma_f32_16x16x32_bf16(
                    af[mi][ks], bfr[ni][ks], acc[mi][ni], 0, 0, 0);
}

__device__ __forceinline__ void store_c(float* C, size_t i, float v) { C[i] = v; }
__device__ __forceinline__ void store_c(unsigned short* C, size_t i, float v) { C[i] = f2bf(v); }

// C/D layout (m89-verified): col = lane&15, row = quad*4 + reg
template <int TM, int TN, typename CT>
__device__ __forceinline__ void epilogue(CT* __restrict__ C, f32x4 (&acc)[TM / 32][TN / 32],
                                         int rowBase, int colBase, int ldc, float alpha,
                                         int wr, int wc, int l15, int quad)
{
    #pragma unroll
    for (int mi = 0; mi < TM / 32; ++mi)
        #pragma unroll
        for (int ni = 0; ni < TN / 32; ++ni) {
            int col = colBase + wc + ni * 16 + l15;
            #pragma unroll
            for (int r = 0; r < 4; ++r) {
                int row = rowBase + wr + mi * 16 + quad * 4 + r;
                store_c(C, (size_t)row * ldc + col, alpha * acc[mi][ni][r]);
            }
        }
}

// ---- 32x32 transpose tile: X fp32 -> Xt bf16 [D][S] and Xbf bf16 [S][D] ----
__device__ void transp_tile(const float* __restrict__ X, unsigned short* __restrict__ Xt,
                            unsigned short* __restrict__ Xbf, int bb, int s0, int d0,
                            unsigned short* tbuf /* 32*36 */)
{
    const float* Xb = X + (size_t)bb * 2048 * 768;
    unsigned short* Xtb = Xt + (size_t)bb * 2048 * 768;
    unsigned short* Xbb = Xbf + (size_t)bb * 2048 * 768;
    const int tx = threadIdx.x & 7, ty = threadIdx.x >> 3;

    float4 v = *reinterpret_cast<const float4*>(&Xb[(size_t)(s0 + ty) * 768 + d0 + tx * 4]);
    ushort4 pk;
    pk.x = f2bf(v.x); pk.y = f2bf(v.y); pk.z = f2bf(v.z); pk.w = f2bf(v.w);
    *reinterpret_cast<ushort4*>(&Xbb[(size_t)(s0 + ty) * 768 + d0 + tx * 4]) = pk;
    tbuf[(tx * 4 + 0) * 36 + ty] = pk.x;
    tbuf[(tx * 4 + 1) * 36 + ty] = pk.y;
    tbuf[(tx * 4 + 2) * 36 + ty] = pk.z;
    tbuf[(tx * 4 + 3) * 36 + ty] = pk.w;
    __syncthreads();
    ushort4 o;
    o.x = tbuf[ty * 36 + tx * 4 + 0];
    o.y = tbuf[ty * 36 + tx * 4 + 1];
    o.z = tbuf[ty * 36 + tx * 4 + 2];
    o.w = tbuf[ty * 36 + tx * 4 + 3];
    *reinterpret_cast<ushort4*>(&Xtb[(size_t)(d0 + ty) * 2048 + s0 + tx * 4]) = o;
}

// ---- prep: blocks 0..143 = P tiles (64x64 from fp32 W); rest = transpose ----
__global__ __launch_bounds__(256)
void prep(const float* __restrict__ X, const float* __restrict__ Wq,
          const float* __restrict__ Wk, unsigned short* __restrict__ Xt,
          unsigned short* __restrict__ Xbf, unsigned short* __restrict__ P16)
{
    __shared__ unsigned short lds[(64 + 64) * 64];   // 16 KB
    const int blk = blockIdx.x;
    const int tid = threadIdx.x, lane = tid & 63, wave = tid >> 6;
    const int l15 = lane & 15, quad = lane >> 4;

    if (blk < 144) {                       // P = Wq * Wk^T, tile (ty,tz) of 64
        const int ty = blk / 12, tz = blk - ty * 12;
        const int wr = (wave >> 1) * 32, wc = (wave & 1) * 32;
        f32x4 acc[2][2] = {};
        for (int k0 = 0; k0 < 768; k0 += 64) {
            stage_f32<64>(Wq + (size_t)ty * 64 * 768 + k0, lds, 768, tid);
            stage_f32<64>(Wk + (size_t)tz * 64 * 768 + k0, lds + 64 * 64, 768, tid);
            __syncthreads();
            mfma_step<64, 64>(lds, lds + 64 * 64, acc, wr, wc, l15, quad);
            __syncthreads();
        }
        epilogue<64, 64, unsigned short>(P16, acc, ty * 64, tz * 64, 768, 1.0f,
                                         wr, wc, l15, quad);
    } else {                               // transpose: 1536 tiles per batch
        const int t0 = blk - 144;
        const int b = t0 / 1536, t = t0 - b * 1536;
        transp_tile(X, Xt, Xbf, b, (t & 63) * 32, (t >> 6) * 32, lds);
    }
}

// ---- G split-K: Gks_b = Xt_b[:, ks*1024 : +1024] * (same)^T, fp32 out ----
__global__ __launch_bounds__(256)
void gemm_G(const unsigned short* __restrict__ Xt, float* __restrict__ Ga,
            float* __restrict__ Gb)
{
    __shared__ unsigned short lds[(96 + 96) * 64];   // 24 KB -> cap 6/CU
    const int b = blockIdx.x, ty = blockIdx.y;
    const int tz = blockIdx.z >> 1, ks = blockIdx.z & 1;
    const int tid = threadIdx.x, lane = tid & 63, wave = tid >> 6;
    const int wr = (wave >> 1) * 48, wc = (wave & 1) * 48;
    const int l15 = lane & 15, quad = lane >> 4;

    const unsigned short* Xtb = Xt + (size_t)b * 768 * 2048;
    const unsigned short* A0 = Xtb + (size_t)ty * 96 * 2048 + ks * 1024;
    const unsigned short* B0 = Xtb + (size_t)tz * 96 * 2048 + ks * 1024;
    float* C = (ks ? Gb : Ga) + (size_t)b * 768 * 768;

    f32x4 acc[3][3] = {};
    for (int k0 = 0; k0 < 1024; k0 += 64) {
        stage_glds<96>(A0 + k0, lds, 2048, tid);
        stage_glds<96>(B0 + k0, lds + 96 * 64, 2048, tid);
        __syncthreads();
        mfma_step<96, 96>(lds, lds + 96 * 64, acc, wr, wc, l15, quad);
        __syncthreads();
    }
    epilogue<96, 96, float>(C, acc, ty * 96, tz * 96, 768, 1.0f, wr, wc, l15, quad);
}

// ---- Ht = alpha * (Ga+Gb) * P^T ; A staged from fp32 pair, B via glds ----
__global__ __launch_bounds__(256)
void gemm_Ht(const float* __restrict__ Ga, const float* __restrict__ Gb,
             const unsigned short* __restrict__ P16, unsigned short* __restrict__ Ht,
             float alpha)
{
    __shared__ unsigned short lds[(64 + 64) * 64];   // 16 KB -> cap 10/CU
    const int b = blockIdx.x, ty = blockIdx.y, tz = blockIdx.z;
    const int tid = threadIdx.x, lane = tid & 63, wave = tid >> 6;
    const int wr = (wave >> 1) * 32, wc = (wave & 1) * 32;
    const int l15 = lane & 15, quad = lane >> 4;

    const float* Ab = Ga + (size_t)b * 768 * 768 + (size_t)ty * 64 * 768;
    const float* Bb = Gb + (size_t)b * 768 * 768 + (size_t)ty * 64 * 768;
    const unsigned short* B0 = P16 + (size_t)tz * 64 * 768;

    f32x4 acc[2][2] = {};
    for (int k0 = 0; k0 < 768; k0 += 64) {
        stage_f32pair<64>(Ab + k0, Bb + k0, lds, 768, tid);
        stage_glds<64>(B0 + k0, lds + 64 * 64, 768, tid);
        __syncthreads();
        mfma_step<64, 64>(lds, lds + 64 * 64, acc, wr, wc, l15, quad);
        __syncthreads();
    }
    epilogue<64, 64, unsigned short>(Ht + (size_t)b * 768 * 768, acc,
                                     ty * 64, tz * 64, 768, alpha, wr, wc, l15, quad);
}

// ---- out = Xbf * Ht^T ; 128x64 tiles (grid 6/CU, all co-resident) ----
__global__ __launch_bounds__(256)
void gemm_out(const unsigned short* __restrict__ Xbf, const unsigned short* __restrict__ Ht,
              float* __restrict__ out)
{
    __shared__ unsigned short lds[(128 + 64) * 64];  // 24 KB -> cap 6/CU
    const int b = blockIdx.x, ty = blockIdx.y, tz = blockIdx.z;
    const int tid = threadIdx.x, lane = tid & 63, wave = tid >> 6;
    const int wr = (wave >> 1) * 64, wc = (wave & 1) * 32;
    const int l15 = lane & 15, quad = lane >> 4;

    const unsigned short* A0 = Xbf + (size_t)b * 2048 * 768 + (size_t)ty * 128 * 768;
    const unsigned short* B0 = Ht + (size_t)b * 768 * 768 + (size_t)tz * 64 * 768;

    f32x4 acc[4][2] = {};
    for (int k0 = 0; k0 < 768; k0 += 64) {
        stage_glds<128>(A0 + k0, lds, 768, tid);
        stage_glds<64>(B0 + k0, lds + 128 * 64, 768, tid);
        __syncthreads();
        mfma_step<128, 64>(lds, lds + 128 * 64, acc, wr, wc, l15, quad);
        __syncthreads();
    }
    epilogue<128, 64, float>(out + (size_t)b * 2048 * 768, acc,
                             ty * 128, tz * 64, 768, 1.0f, wr, wc, l15, quad);
}

extern "C" void kernel_launch(void* const* d_in, const int* in_sizes, int n_in,
                              void* d_out, int out_size, void* d_ws, size_t ws_size,
                              hipStream_t stream)
{
    const float* X  = (const float*)d_in[0];  // [8,2048,768] fp32
    const float* Wq = (const float*)d_in[2];  // [768,768]
    const float* Wk = (const float*)d_in[3];  // [768,768]
    float* out = (float*)d_out;               // [8,2048,768] fp32

    const int Bn = 8, S = 2048, D = 768;
    const float alpha = 1.0f / (768.0f * sqrtf(768.0f));  // 1/768^1.5
    const size_t szX  = (size_t)Bn * S * D;   // ushort elements
    const size_t szDD = (size_t)Bn * D * D;

    // ws: Xt | Xbf | P16 | Ga(f32) | Gb(f32) | Ht  (~98.7 MB, ws >= 256MB per fills)
    unsigned short* Xt  = (unsigned short*)d_ws;
    unsigned short* Xbf = Xt + szX;
    unsigned short* P16 = Xbf + szX;
    float* Ga = (float*)(P16 + (size_t)D * D);
    float* Gb = Ga + szDD;
    unsigned short* Ht = (unsigned short*)(Gb + szDD);

    // prep: 144 P-tile blocks first (longest), then 12288 transpose tiles
    prep<<<dim3(144 + Bn * (S / 32) * (D / 32)), 256, 0, stream>>>(X, Wq, Wk, Xt, Xbf, P16);

    // G partials: grid (8,8,16) = 1024 blocks = 4/CU
    gemm_G<<<dim3(Bn, 8, 16), 256, 0, stream>>>(Xt, Ga, Gb);

    // Ht: grid (8,12,12) = 1152 blocks = 4.5/CU
    gemm_Ht<<<dim3(Bn, 12, 12), 256, 0, stream>>>(Ga, Gb, P16, Ht, alpha);

    // out: grid (8,16,12) = 1536 blocks = 6/CU
    gemm_out<<<dim3(Bn, S / 128, 12), 256, 0, stream>>>(Xbf, Ht, out);
}